// Round 1
// baseline (5269.442 us; speedup 1.0000x reference)
//
#include <hip/hip_runtime.h>
#include <cstdint>
#include <cstddef>

typedef unsigned short u16;
typedef unsigned int u32;

typedef short short8 __attribute__((ext_vector_type(8)));
typedef float floatx4 __attribute__((ext_vector_type(4)));

// Problem constants: B=32, T=512, D=256, H=256, 4H=1024, C=32
// Workspace layout (bytes)
#define O_EMB    0ull                 // emb bf16 [16384][256]
#define O_XG     8388608ull           // xg bf16 [2][16384][1024]
#define O_HS     75497472ull          // hs bf16 [2][16384][256]
#define O_HST    92274688ull          // hstate bf16 [2 dir][2 parity][32][256]
#define O_LOGITS 92340224ull          // logits f32 [16384][32]
#define O_FLAGS  94437376ull          // 32 ints
#define O_WIT    94437504ull          // WiT bf16 [2][1024][256]
#define O_OUTW   95486080ull          // outW bf16 [512][32]
#define WS_NEED  95518848ull

__device__ __forceinline__ u16 f2bf(float x) {
    u32 u = __float_as_uint(x);
    u += 0x7fffu + ((u >> 16) & 1u);
    return (u16)(u >> 16);
}
__device__ __forceinline__ float bf2f(u16 v) { return __uint_as_float(((u32)v) << 16); }
__device__ __forceinline__ float sigm(float x) { return 1.0f / (1.0f + __expf(-x)); }
__device__ __forceinline__ float tanh_f(float x) {
    x = fminf(30.0f, fmaxf(-30.0f, x));
    float e = __expf(-2.0f * x);
    return (1.0f - e) / (1.0f + e);
}

// ---------------- K_init: zero h state + sync flags (ws is poisoned each launch) ----
__global__ __launch_bounds__(256) void k_init(u32* hstate_u32, int* flags) {
    int i = blockIdx.x * 256 + threadIdx.x;
    if (i < 16384) hstate_u32[i] = 0u;   // 2*2*32*256 bf16 = 16384 u32
    if (i < 32) flags[i] = 0;
}

// ---------------- K0: Wi -> WiT bf16 (transposed [n][k]), out_W -> bf16 ------------
__global__ __launch_bounds__(256) void k0_prep(const float* __restrict__ Wi_f, const float* __restrict__ Wi_b,
                                               const float* __restrict__ out_W,
                                               u16* __restrict__ WiT, u16* __restrict__ outWb) {
    int id = blockIdx.x * 256 + threadIdx.x;   // grid 2112*256 = 540672 exact
    if (id < 524288) {
        int d = id >> 18;
        int rem = id & 262143;
        int k = rem >> 10;
        int n = rem & 1023;
        const float* Wi = d ? Wi_b : Wi_f;
        WiT[(size_t)d * 262144 + (size_t)n * 256 + k] = f2bf(Wi[(size_t)k * 1024 + n]);
    } else {
        int id2 = id - 524288;                 // < 16384
        outWb[id2] = f2bf(out_W[id2]);
    }
}

// ---------------- K1: embedding gather -> emb bf16 [r=t*32+b][256] -----------------
__global__ __launch_bounds__(256) void k1_embed(const int* __restrict__ chars, const int* __restrict__ bigrams,
                                                const float* __restrict__ ct, const float* __restrict__ bt,
                                                u16* __restrict__ emb) {
    int idx = blockIdx.x * 256 + threadIdx.x;  // grid 8192*256 = 2097152 = 16384*128
    int r = idx >> 7;
    int p2 = (idx & 127) << 1;
    int t = r >> 5, b = r & 31;
    const float* src;
    if (p2 < 128) src = ct + (size_t)chars[b * 512 + t] * 128 + p2;
    else          src = bt + (size_t)bigrams[b * 512 + t] * 128 + (p2 - 128);
    float2 v = *(const float2*)(const void*)src;
    u32 pk = (u32)f2bf(v.x) | ((u32)f2bf(v.y) << 16);
    *(u32*)(void*)(emb + (size_t)r * 256 + p2) = pk;
}

// ---------------- K2: xg[d][r][n] = emb @ Wi_d + b_d  (bf16 MFMA) ------------------
__global__ __launch_bounds__(256) void k2_gemm(const u16* __restrict__ emb, const u16* __restrict__ WiT,
                                               const float* __restrict__ b_f, const float* __restrict__ b_b,
                                               u16* __restrict__ xg) {
    int mbase = blockIdx.x * 64;
    int nbase = blockIdx.y * 64;
    int d = blockIdx.z;
    const u16* Bt = WiT + (size_t)d * 262144;
    const float* bias = d ? b_b : b_f;
    u16* xgd = xg + (size_t)d * 16777216ull;
    int tid = threadIdx.x;
    int wv = tid >> 6, l = tid & 63, lm = l & 15, lq = l >> 4;
    floatx4 acc[4] = {{0,0,0,0},{0,0,0,0},{0,0,0,0},{0,0,0,0}};
    int arow = mbase + wv * 16 + lm;
#pragma unroll
    for (int kc = 0; kc < 8; ++kc) {
        int k0 = kc * 32 + lq * 8;
        short8 a = *(const short8*)(const void*)(emb + (size_t)arow * 256 + k0);
#pragma unroll
        for (int nt = 0; nt < 4; ++nt) {
            short8 bb = *(const short8*)(const void*)(Bt + (size_t)(nbase + nt * 16 + lm) * 256 + k0);
            acc[nt] = __builtin_amdgcn_mfma_f32_16x16x32_bf16(a, bb, acc[nt], 0, 0, 0);
        }
    }
#pragma unroll
    for (int nt = 0; nt < 4; ++nt) {
        int n = nbase + nt * 16 + lm;
        float bv = bias[n];
#pragma unroll
        for (int r = 0; r < 4; ++r) {
            int rr = mbase + wv * 16 + lq * 4 + r;
            xgd[(size_t)rr * 1024 + n] = f2bf(acc[nt][r] + bv);
        }
    }
}

// ---------------- K3: BiLSTM recurrence -------------------------------------------
// 32 blocks: dir = bid>>4, w = bid&15. WG w owns h dims [16w,16w+16) and the 4
// corresponding gate column groups; its Wh slice lives in LDS (bf16, transposed).
// Per step: MFMA [32,256]x[256,64] from (global h, LDS Wh), gates, write h slice,
// flag sync (double-buffered h by step parity; device-scope atomics + threadfence).
__global__ __launch_bounds__(256) void k3_lstm(const u16* __restrict__ xg, const float* __restrict__ Wh_f,
                                               const float* __restrict__ Wh_b, const int* __restrict__ seq_len,
                                               u16* __restrict__ hstate, u16* __restrict__ hs,
                                               int* __restrict__ flags) {
    int bid = blockIdx.x;
    int dir = bid >> 4;
    int w = bid & 15;
    const float* Wh = dir ? Wh_b : Wh_f;
    const u16* xgd = xg + (size_t)dir * 16777216ull;
    u16* hsd = hs + (size_t)dir * 4194304ull;
    __shared__ u16 lds_w[64 * 264];      // [p=g*16+c][k], padded pitch 264
    __shared__ float gate_lds[32 * 68];  // [b][p], padded pitch 68
    int tid = threadIdx.x;

    // Stage Wh slice: cols gcol = g*256 + 16w + c, transposed into lds_w[p][k]
    for (int it = 0; it < 64; ++it) {
        int e = it * 256 + tid;
        int p = e & 63;
        int k = e >> 6;
        int gcol = (p >> 4) * 256 + w * 16 + (p & 15);
        lds_w[p * 264 + k] = f2bf(Wh[(size_t)k * 1024 + gcol]);
    }
    int bcell = tid >> 3, uu = tid & 7, c0 = uu * 2;   // this thread owns cells (bcell, c0..c0+1)
    int L = seq_len[bcell];
    float cst0 = 0.0f, cst1 = 0.0f;
    int wv = tid >> 6, l = tid & 63, lm = l & 15, lq = l >> 4, mt = wv & 1, nh = wv >> 1;
    __syncthreads();

    for (int s = 0; s < 512; ++s) {
        int t = dir ? (511 - s) : s;
        // prefetch xg (independent of sync) : 4 gates x 2 bf16
        u32 xgv[4];
        const u16* xrow = xgd + ((size_t)(t * 32 + bcell)) * 1024 + w * 16 + c0;
#pragma unroll
        for (int g = 0; g < 4; ++g) xgv[g] = *(const u32*)(const void*)(xrow + g * 256);

        if (s > 0) {
            if (tid < 16) {
                while (__hip_atomic_load(&flags[dir * 16 + tid], __ATOMIC_RELAXED, __HIP_MEMORY_SCOPE_AGENT) < s) {}
            }
            __syncthreads();
            __threadfence();   // acquire: make other WGs' h writes visible (L1 inval)
        }
        const u16* hb = hstate + ((size_t)(dir * 2 + (s & 1))) * 8192;
        floatx4 acc0 = {0,0,0,0}, acc1 = {0,0,0,0};
        int arowh = mt * 16 + lm;
#pragma unroll
        for (int kc = 0; kc < 8; ++kc) {
            int k0 = kc * 32 + lq * 8;
            short8 a = *(const short8*)(const void*)(hb + arowh * 256 + k0);
            short8 b0 = *(const short8*)(const void*)&lds_w[(nh * 32 + lm) * 264 + k0];
            acc0 = __builtin_amdgcn_mfma_f32_16x16x32_bf16(a, b0, acc0, 0, 0, 0);
            short8 b1 = *(const short8*)(const void*)&lds_w[(nh * 32 + 16 + lm) * 264 + k0];
            acc1 = __builtin_amdgcn_mfma_f32_16x16x32_bf16(a, b1, acc1, 0, 0, 0);
        }
#pragma unroll
        for (int r = 0; r < 4; ++r) {
            int b2 = mt * 16 + lq * 4 + r;
            gate_lds[b2 * 68 + nh * 32 + lm] = acc0[r];
            gate_lds[b2 * 68 + nh * 32 + 16 + lm] = acc1[r];
        }
        __syncthreads();
        float hv0, hv1;
#pragma unroll
        for (int r = 0; r < 2; ++r) {
            int cc = c0 + r;
            float gi = gate_lds[bcell * 68 + cc]      + bf2f((u16)(xgv[0] >> (16 * r)));
            float gf = gate_lds[bcell * 68 + 16 + cc] + bf2f((u16)(xgv[1] >> (16 * r)));
            float gg = gate_lds[bcell * 68 + 32 + cc] + bf2f((u16)(xgv[2] >> (16 * r)));
            float go = gate_lds[bcell * 68 + 48 + cc] + bf2f((u16)(xgv[3] >> (16 * r)));
            float ig = sigm(gi), fg = sigm(gf), gt = tanh_f(gg), og = sigm(go);
            float cs = r ? cst1 : cst0;
            float cn = fg * cs + ig * gt;
            float hn = og * tanh_f(cn);
            if (dir && t >= L) { cn = cs; hn = 0.0f; }   // backward: masked prefix carries zeros
            if (r) { cst1 = cn; hv1 = hn; } else { cst0 = cn; hv0 = hn; }
        }
        u32 hpack = (u32)f2bf(hv0) | ((u32)f2bf(hv1) << 16);
        u16* hbn = hstate + ((size_t)(dir * 2 + ((s + 1) & 1))) * 8192;
        *(u32*)(void*)(hbn + bcell * 256 + w * 16 + c0) = hpack;
        *(u32*)(void*)(hsd + ((size_t)(t * 32 + bcell)) * 256 + w * 16 + c0) = hpack;
        __threadfence();      // release: writes device-visible before flag
        __syncthreads();
        if (tid == 0) __hip_atomic_store(&flags[dir * 16 + w], s + 1, __ATOMIC_RELEASE, __HIP_MEMORY_SCOPE_AGENT);
    }
}

// ---------------- K4: logits = log_softmax([hf;hb] @ out_W + out_b) ---------------
__global__ __launch_bounds__(256) void k4_proj(const u16* __restrict__ hs, const u16* __restrict__ outWb,
                                               const float* __restrict__ out_b, float* __restrict__ logits) {
    int r = blockIdx.x * 8 + (threadIdx.x >> 5);
    int n = threadIdx.x & 31;
    const u16* hf = hs + (size_t)r * 256;
    const u16* hbk = hs + 4194304ull + (size_t)r * 256;
    float acc = out_b[n];
#pragma unroll 4
    for (int k = 0; k < 256; k += 2) {
        u32 hv = *(const u32*)(const void*)(hf + k);
        acc += bf2f((u16)hv) * bf2f(outWb[k * 32 + n]);
        acc += bf2f((u16)(hv >> 16)) * bf2f(outWb[(k + 1) * 32 + n]);
    }
#pragma unroll 4
    for (int k = 0; k < 256; k += 2) {
        u32 hv = *(const u32*)(const void*)(hbk + k);
        acc += bf2f((u16)hv) * bf2f(outWb[(256 + k) * 32 + n]);
        acc += bf2f((u16)(hv >> 16)) * bf2f(outWb[(257 + k) * 32 + n]);
    }
    float m = acc;
#pragma unroll
    for (int d2 = 16; d2 >= 1; d2 >>= 1) m = fmaxf(m, __shfl_xor(m, d2, 32));
    float s = __expf(acc - m);
#pragma unroll
    for (int d2 = 16; d2 >= 1; d2 >>= 1) s += __shfl_xor(s, d2, 32);
    logits[(size_t)r * 32 + n] = acc - m - __logf(s);
}

// ---------------- K5: CRF forward + gold score -> out[b] --------------------------
__global__ __launch_bounds__(256) void k5_crf(const float* __restrict__ logits, const int* __restrict__ target,
                                              const int* __restrict__ seq_len, const float* __restrict__ trans,
                                              const float* __restrict__ start_trans, const float* __restrict__ end_trans,
                                              float* __restrict__ out) {
    int b = blockIdx.x;
    int tid = threadIdx.x;
    int L = seq_len[b];
    __shared__ float alpha[32];
    __shared__ float red[4];
    __shared__ float goldsh;

    // gold path score
    float part = 0.0f;
    for (int t = tid; t < 512; t += 256) {
        if (t < L) {
            int tg = target[b * 512 + t];
            part += logits[((size_t)(t * 32 + b)) * 32 + tg];
            if (t >= 1) part += trans[target[b * 512 + t - 1] * 32 + tg];
        }
    }
#pragma unroll
    for (int d2 = 32; d2 >= 1; d2 >>= 1) part += __shfl_xor(part, d2, 64);
    if ((tid & 63) == 0) red[tid >> 6] = part;
    __syncthreads();
    if (tid == 0) {
        float g = red[0] + red[1] + red[2] + red[3];
        g += start_trans[target[b * 512]];
        g += end_trans[target[b * 512 + L - 1]];
        goldsh = g;
    }
    if (tid < 32) alpha[tid] = logits[(size_t)b * 32 + tid] + start_trans[tid];
    __syncthreads();

    int j = tid >> 3, uu = tid & 7;
    float tr4[4];
#pragma unroll
    for (int r = 0; r < 4; ++r) tr4[r] = trans[(uu * 4 + r) * 32 + j];
    float e_next = logits[((size_t)(32 + b)) * 32 + j];
    for (int t = 1; t < 512; ++t) {
        float e = e_next;
        if (t < 511) e_next = logits[((size_t)((t + 1) * 32 + b)) * 32 + j];
        float a0 = alpha[uu * 4 + 0] + tr4[0];
        float a1 = alpha[uu * 4 + 1] + tr4[1];
        float a2 = alpha[uu * 4 + 2] + tr4[2];
        float a3 = alpha[uu * 4 + 3] + tr4[3];
        float m = fmaxf(fmaxf(a0, a1), fmaxf(a2, a3));
#pragma unroll
        for (int d2 = 4; d2 >= 1; d2 >>= 1) m = fmaxf(m, __shfl_xor(m, d2, 8));
        float ss = __expf(a0 - m) + __expf(a1 - m) + __expf(a2 - m) + __expf(a3 - m);
#pragma unroll
        for (int d2 = 4; d2 >= 1; d2 >>= 1) ss += __shfl_xor(ss, d2, 8);
        float nv = e + m + __logf(ss);
        __syncthreads();
        if (uu == 0 && t < L) alpha[j] = nv;
        __syncthreads();
    }
    if (tid < 32) {
        float v = alpha[tid] + end_trans[tid];
        float m = v;
#pragma unroll
        for (int d2 = 16; d2 >= 1; d2 >>= 1) m = fmaxf(m, __shfl_xor(m, d2, 32));
        float s2 = __expf(v - m);
#pragma unroll
        for (int d2 = 16; d2 >= 1; d2 >>= 1) s2 += __shfl_xor(s2, d2, 32);
        if (tid == 0) out[b] = m + __logf(s2) - goldsh;
    }
}

extern "C" void kernel_launch(void* const* d_in, const int* in_sizes, int n_in,
                              void* d_out, int out_size, void* d_ws, size_t ws_size,
                              hipStream_t stream) {
    if (ws_size < WS_NEED) return;  // workspace too small: fail cleanly, no OOB
    const int* chars = (const int*)d_in[0];
    const int* bigrams = (const int*)d_in[1];
    const int* seq_len = (const int*)d_in[2];
    const int* target = (const int*)d_in[3];
    const float* char_table = (const float*)d_in[4];
    const float* bigram_table = (const float*)d_in[5];
    const float* Wi_f = (const float*)d_in[6];
    const float* Wh_f = (const float*)d_in[7];
    const float* b_f = (const float*)d_in[8];
    const float* Wi_b = (const float*)d_in[9];
    const float* Wh_b = (const float*)d_in[10];
    const float* b_b = (const float*)d_in[11];
    const float* out_W = (const float*)d_in[12];
    const float* out_b = (const float*)d_in[13];
    const float* trans = (const float*)d_in[14];
    const float* start_trans = (const float*)d_in[15];
    const float* end_trans = (const float*)d_in[16];

    char* ws = (char*)d_ws;
    u16* emb = (u16*)(ws + O_EMB);
    u16* xg = (u16*)(ws + O_XG);
    u16* hs = (u16*)(ws + O_HS);
    u16* hst = (u16*)(ws + O_HST);
    float* logits = (float*)(ws + O_LOGITS);
    int* flags = (int*)(ws + O_FLAGS);
    u16* WiT = (u16*)(ws + O_WIT);
    u16* outWb = (u16*)(ws + O_OUTW);

    hipLaunchKernelGGL(k_init, dim3(64), dim3(256), 0, stream, (u32*)hst, flags);
    hipLaunchKernelGGL(k0_prep, dim3(2112), dim3(256), 0, stream, Wi_f, Wi_b, out_W, WiT, outWb);
    hipLaunchKernelGGL(k1_embed, dim3(8192), dim3(256), 0, stream, chars, bigrams, char_table, bigram_table, emb);
    hipLaunchKernelGGL(k2_gemm, dim3(256, 16, 2), dim3(256), 0, stream, emb, WiT, b_f, b_b, xg);
    hipLaunchKernelGGL(k3_lstm, dim3(32), dim3(256), 0, stream, xg, Wh_f, Wh_b, seq_len, hst, hs, flags);
    hipLaunchKernelGGL(k4_proj, dim3(2048), dim3(256), 0, stream, hs, outWb, out_b, logits);
    hipLaunchKernelGGL(k5_crf, dim3(32), dim3(256), 0, stream, logits, target, seq_len, trans, start_trans, end_trans,
                       (float*)d_out);
}

// Round 2
// 2881.881 us; speedup vs baseline: 1.8285x; 1.8285x over previous
//
#include <hip/hip_runtime.h>
#include <cstdint>
#include <cstddef>

typedef unsigned short u16;
typedef unsigned int u32;
typedef unsigned long long u64;

typedef short short8 __attribute__((ext_vector_type(8)));
typedef float floatx4 __attribute__((ext_vector_type(4)));

// Problem constants: B=32, T=512, D=256, H=256, 4H=1024, C=32
// Workspace layout (bytes)
#define O_EMB    0ull                 // emb bf16 [16384][256]
#define O_XG     8388608ull           // xg bf16 [2][16384][1024]
#define O_HS     75497472ull          // hs bf16 [2][16384][256]
#define O_HST    92274688ull          // hstate bf16 [2 dir][2 parity][32][256]
#define O_LOGITS 92340224ull          // logits f32 [16384][32]
#define O_FLAGS  94437376ull          // 32 ints
#define O_WIT    94437504ull          // WiT bf16 [2][1024][256]
#define O_OUTW   95486080ull          // outW bf16 [512][32]
#define WS_NEED  95518848ull

__device__ __forceinline__ u16 f2bf(float x) {
    u32 u = __float_as_uint(x);
    u += 0x7fffu + ((u >> 16) & 1u);
    return (u16)(u >> 16);
}
__device__ __forceinline__ float bf2f(u16 v) { return __uint_as_float(((u32)v) << 16); }
__device__ __forceinline__ float sigm(float x) { return 1.0f / (1.0f + __expf(-x)); }
__device__ __forceinline__ float tanh_f(float x) {
    x = fminf(30.0f, fmaxf(-30.0f, x));
    float e = __expf(-2.0f * x);
    return (1.0f - e) / (1.0f + e);
}

// ---------------- K_init: zero h state + sync flags (ws is poisoned each launch) ----
__global__ __launch_bounds__(256) void k_init(u32* hstate_u32, int* flags) {
    int i = blockIdx.x * 256 + threadIdx.x;
    if (i < 16384) hstate_u32[i] = 0u;   // 2*2*32*256 bf16 = 16384 u32
    if (i < 32) flags[i] = 0;
}

// ---------------- K0: Wi -> WiT bf16 (transposed [n][k]), out_W -> bf16 ------------
__global__ __launch_bounds__(256) void k0_prep(const float* __restrict__ Wi_f, const float* __restrict__ Wi_b,
                                               const float* __restrict__ out_W,
                                               u16* __restrict__ WiT, u16* __restrict__ outWb) {
    int id = blockIdx.x * 256 + threadIdx.x;   // grid 2112*256 = 540672 exact
    if (id < 524288) {
        int d = id >> 18;
        int rem = id & 262143;
        int k = rem >> 10;
        int n = rem & 1023;
        const float* Wi = d ? Wi_b : Wi_f;
        WiT[(size_t)d * 262144 + (size_t)n * 256 + k] = f2bf(Wi[(size_t)k * 1024 + n]);
    } else {
        int id2 = id - 524288;                 // < 16384
        outWb[id2] = f2bf(out_W[id2]);
    }
}

// ---------------- K1: embedding gather -> emb bf16 [r=t*32+b][256] -----------------
__global__ __launch_bounds__(256) void k1_embed(const int* __restrict__ chars, const int* __restrict__ bigrams,
                                                const float* __restrict__ ct, const float* __restrict__ bt,
                                                u16* __restrict__ emb) {
    int idx = blockIdx.x * 256 + threadIdx.x;  // grid 8192*256 = 2097152 = 16384*128
    int r = idx >> 7;
    int p2 = (idx & 127) << 1;
    int t = r >> 5, b = r & 31;
    const float* src;
    if (p2 < 128) src = ct + (size_t)chars[b * 512 + t] * 128 + p2;
    else          src = bt + (size_t)bigrams[b * 512 + t] * 128 + (p2 - 128);
    float2 v = *(const float2*)(const void*)src;
    u32 pk = (u32)f2bf(v.x) | ((u32)f2bf(v.y) << 16);
    *(u32*)(void*)(emb + (size_t)r * 256 + p2) = pk;
}

// ---------------- K2: xg[d][r][n] = emb @ Wi_d + b_d  (bf16 MFMA) ------------------
__global__ __launch_bounds__(256) void k2_gemm(const u16* __restrict__ emb, const u16* __restrict__ WiT,
                                               const float* __restrict__ b_f, const float* __restrict__ b_b,
                                               u16* __restrict__ xg) {
    int mbase = blockIdx.x * 64;
    int nbase = blockIdx.y * 64;
    int d = blockIdx.z;
    const u16* Bt = WiT + (size_t)d * 262144;
    const float* bias = d ? b_b : b_f;
    u16* xgd = xg + (size_t)d * 16777216ull;
    int tid = threadIdx.x;
    int wv = tid >> 6, l = tid & 63, lm = l & 15, lq = l >> 4;
    floatx4 acc[4] = {{0,0,0,0},{0,0,0,0},{0,0,0,0},{0,0,0,0}};
    int arow = mbase + wv * 16 + lm;
#pragma unroll
    for (int kc = 0; kc < 8; ++kc) {
        int k0 = kc * 32 + lq * 8;
        short8 a = *(const short8*)(const void*)(emb + (size_t)arow * 256 + k0);
#pragma unroll
        for (int nt = 0; nt < 4; ++nt) {
            short8 bb = *(const short8*)(const void*)(Bt + (size_t)(nbase + nt * 16 + lm) * 256 + k0);
            acc[nt] = __builtin_amdgcn_mfma_f32_16x16x32_bf16(a, bb, acc[nt], 0, 0, 0);
        }
    }
#pragma unroll
    for (int nt = 0; nt < 4; ++nt) {
        int n = nbase + nt * 16 + lm;
        float bv = bias[n];
#pragma unroll
        for (int r = 0; r < 4; ++r) {
            int rr = mbase + wv * 16 + lq * 4 + r;
            xgd[(size_t)rr * 1024 + n] = f2bf(acc[nt][r] + bv);
        }
    }
}

// ---------------- K3: BiLSTM recurrence -------------------------------------------
// 32 blocks: dir = bid>>4, w = bid&15. WG w owns h dims [16w,16w+16); Wh slice in LDS.
// Cross-block h exchange uses agent-scope RELAXED atomics exclusively (write-through /
// L2-bypass, coherent at L3) -> NO threadfence (no buffer_inv/wbl2 bulk cache ops in
// the hot loop, which dominated R1 at 8.9us/step). Flag release-store is the only
// fence and finds no dirty L2 lines.
__global__ __launch_bounds__(256) void k3_lstm(const u16* __restrict__ xg, const float* __restrict__ Wh_f,
                                               const float* __restrict__ Wh_b, const int* __restrict__ seq_len,
                                               u16* __restrict__ hstate, u16* __restrict__ hs,
                                               int* __restrict__ flags) {
    int bid = blockIdx.x;
    int dir = bid >> 4;
    int w = bid & 15;
    const float* Wh = dir ? Wh_b : Wh_f;
    const u16* xgd = xg + (size_t)dir * 16777216ull;
    u16* hsd = hs + (size_t)dir * 4194304ull;
    __shared__ u16 lds_w[64 * 264];      // [p=g*16+c][k], padded pitch 264
    __shared__ float gate_lds[32 * 68];  // [b][p], padded pitch 68
    int tid = threadIdx.x;

    // Stage Wh slice: cols gcol = g*256 + 16w + c, transposed into lds_w[p][k]
    for (int it = 0; it < 64; ++it) {
        int e = it * 256 + tid;
        int p = e & 63;
        int k = e >> 6;
        int gcol = (p >> 4) * 256 + w * 16 + (p & 15);
        lds_w[p * 264 + k] = f2bf(Wh[(size_t)k * 1024 + gcol]);
    }
    int bcell = tid >> 3, uu = tid & 7, c0 = uu * 2;   // this thread owns cells (bcell, c0..c0+1)
    int L = seq_len[bcell];
    float cst0 = 0.0f, cst1 = 0.0f;
    int wv = tid >> 6, l = tid & 63, lm = l & 15, lq = l >> 4, mt = wv & 1, nh = wv >> 1;
    int* myflags = flags + dir * 16;
    __syncthreads();

    for (int s = 0; s < 512; ++s) {
        int t = dir ? (511 - s) : s;
        // prefetch xg (independent of sync) : 4 gates x 2 bf16
        u32 xgv[4];
        const u16* xrow = xgd + ((size_t)(t * 32 + bcell)) * 1024 + w * 16 + c0;
#pragma unroll
        for (int g = 0; g < 4; ++g) xgv[g] = *(const u32*)(const void*)(xrow + g * 256);

        if (s > 0) {
            // every wave polls the flag line itself (lane l&15); no barrier, no fence
            while (__hip_atomic_load(&myflags[l & 15], __ATOMIC_RELAXED, __HIP_MEMORY_SCOPE_AGENT) < s) {}
        }
        // A-fragments straight from coherent (L3) atomic u64 loads
        const u64* hbq = (const u64*)(const void*)(hstate + ((size_t)(dir * 2 + (s & 1))) * 8192);
        int arowh = mt * 16 + lm;
        u64 aq[16];
#pragma unroll
        for (int kc = 0; kc < 8; ++kc) {
            size_t qi = (size_t)arowh * 64 + (size_t)kc * 8 + lq * 2;
            aq[2 * kc]     = __hip_atomic_load(hbq + qi,     __ATOMIC_RELAXED, __HIP_MEMORY_SCOPE_AGENT);
            aq[2 * kc + 1] = __hip_atomic_load(hbq + qi + 1, __ATOMIC_RELAXED, __HIP_MEMORY_SCOPE_AGENT);
        }
        floatx4 acc0 = {0,0,0,0}, acc1 = {0,0,0,0};
#pragma unroll
        for (int kc = 0; kc < 8; ++kc) {
            union { u64 q[2]; short8 s8; } ua;
            ua.q[0] = aq[2 * kc];
            ua.q[1] = aq[2 * kc + 1];
            int k0 = kc * 32 + lq * 8;
            short8 b0 = *(const short8*)(const void*)&lds_w[(nh * 32 + lm) * 264 + k0];
            acc0 = __builtin_amdgcn_mfma_f32_16x16x32_bf16(ua.s8, b0, acc0, 0, 0, 0);
            short8 b1 = *(const short8*)(const void*)&lds_w[(nh * 32 + 16 + lm) * 264 + k0];
            acc1 = __builtin_amdgcn_mfma_f32_16x16x32_bf16(ua.s8, b1, acc1, 0, 0, 0);
        }
#pragma unroll
        for (int r = 0; r < 4; ++r) {
            int b2 = mt * 16 + lq * 4 + r;
            gate_lds[b2 * 68 + nh * 32 + lm] = acc0[r];
            gate_lds[b2 * 68 + nh * 32 + 16 + lm] = acc1[r];
        }
        __syncthreads();
        float hv0, hv1;
#pragma unroll
        for (int r = 0; r < 2; ++r) {
            int cc = c0 + r;
            float gi = gate_lds[bcell * 68 + cc]      + bf2f((u16)(xgv[0] >> (16 * r)));
            float gf = gate_lds[bcell * 68 + 16 + cc] + bf2f((u16)(xgv[1] >> (16 * r)));
            float gg = gate_lds[bcell * 68 + 32 + cc] + bf2f((u16)(xgv[2] >> (16 * r)));
            float go = gate_lds[bcell * 68 + 48 + cc] + bf2f((u16)(xgv[3] >> (16 * r)));
            float ig = sigm(gi), fg = sigm(gf), gt = tanh_f(gg), og = sigm(go);
            float cs = r ? cst1 : cst0;
            float cn = fg * cs + ig * gt;
            float hn = og * tanh_f(cn);
            if (dir && t >= L) { cn = cs; hn = 0.0f; }   // backward: masked prefix carries zeros
            if (r) { cst1 = cn; hv1 = hn; } else { cst0 = cn; hv0 = hn; }
        }
        u32 hpack = (u32)f2bf(hv0) | ((u32)f2bf(hv1) << 16);
        u32* hbn = (u32*)(void*)(hstate + ((size_t)(dir * 2 + ((s + 1) & 1))) * 8192 + bcell * 256 + w * 16 + c0);
        __hip_atomic_store(hbn, hpack, __ATOMIC_RELAXED, __HIP_MEMORY_SCOPE_AGENT);
        __hip_atomic_store((u32*)(void*)(hsd + ((size_t)(t * 32 + bcell)) * 256 + w * 16 + c0), hpack,
                           __ATOMIC_RELAXED, __HIP_MEMORY_SCOPE_AGENT);
        __syncthreads();   // all waves' write-through stores vmcnt-drained before flag
        if (tid == 0) __hip_atomic_store(&myflags[w], s + 1, __ATOMIC_RELEASE, __HIP_MEMORY_SCOPE_AGENT);
    }
}

// ---------------- K4: logits = log_softmax([hf;hb] @ out_W + out_b) ---------------
__global__ __launch_bounds__(256) void k4_proj(const u16* __restrict__ hs, const u16* __restrict__ outWb,
                                               const float* __restrict__ out_b, float* __restrict__ logits) {
    int r = blockIdx.x * 8 + (threadIdx.x >> 5);
    int n = threadIdx.x & 31;
    const u16* hf = hs + (size_t)r * 256;
    const u16* hbk = hs + 4194304ull + (size_t)r * 256;
    float acc = out_b[n];
#pragma unroll 4
    for (int k = 0; k < 256; k += 2) {
        u32 hv = *(const u32*)(const void*)(hf + k);
        acc += bf2f((u16)hv) * bf2f(outWb[k * 32 + n]);
        acc += bf2f((u16)(hv >> 16)) * bf2f(outWb[(k + 1) * 32 + n]);
    }
#pragma unroll 4
    for (int k = 0; k < 256; k += 2) {
        u32 hv = *(const u32*)(const void*)(hbk + k);
        acc += bf2f((u16)hv) * bf2f(outWb[(256 + k) * 32 + n]);
        acc += bf2f((u16)(hv >> 16)) * bf2f(outWb[(257 + k) * 32 + n]);
    }
    float m = acc;
#pragma unroll
    for (int d2 = 16; d2 >= 1; d2 >>= 1) m = fmaxf(m, __shfl_xor(m, d2, 32));
    float s = __expf(acc - m);
#pragma unroll
    for (int d2 = 16; d2 >= 1; d2 >>= 1) s += __shfl_xor(s, d2, 32);
    logits[(size_t)r * 32 + n] = acc - m - __logf(s);
}

// ---------------- K5: CRF forward + gold score -> out[b] --------------------------
__global__ __launch_bounds__(256) void k5_crf(const float* __restrict__ logits, const int* __restrict__ target,
                                              const int* __restrict__ seq_len, const float* __restrict__ trans,
                                              const float* __restrict__ start_trans, const float* __restrict__ end_trans,
                                              float* __restrict__ out) {
    int b = blockIdx.x;
    int tid = threadIdx.x;
    int L = seq_len[b];
    __shared__ float alpha[32];
    __shared__ float red[4];
    __shared__ float goldsh;

    // gold path score
    float part = 0.0f;
    for (int t = tid; t < 512; t += 256) {
        if (t < L) {
            int tg = target[b * 512 + t];
            part += logits[((size_t)(t * 32 + b)) * 32 + tg];
            if (t >= 1) part += trans[target[b * 512 + t - 1] * 32 + tg];
        }
    }
#pragma unroll
    for (int d2 = 32; d2 >= 1; d2 >>= 1) part += __shfl_xor(part, d2, 64);
    if ((tid & 63) == 0) red[tid >> 6] = part;
    __syncthreads();
    if (tid == 0) {
        float g = red[0] + red[1] + red[2] + red[3];
        g += start_trans[target[b * 512]];
        g += end_trans[target[b * 512 + L - 1]];
        goldsh = g;
    }
    if (tid < 32) alpha[tid] = logits[(size_t)b * 32 + tid] + start_trans[tid];
    __syncthreads();

    int j = tid >> 3, uu = tid & 7;
    float tr4[4];
#pragma unroll
    for (int r = 0; r < 4; ++r) tr4[r] = trans[(uu * 4 + r) * 32 + j];
    float e_next = logits[((size_t)(32 + b)) * 32 + j];
    for (int t = 1; t < 512; ++t) {
        float e = e_next;
        if (t < 511) e_next = logits[((size_t)((t + 1) * 32 + b)) * 32 + j];
        float a0 = alpha[uu * 4 + 0] + tr4[0];
        float a1 = alpha[uu * 4 + 1] + tr4[1];
        float a2 = alpha[uu * 4 + 2] + tr4[2];
        float a3 = alpha[uu * 4 + 3] + tr4[3];
        float m = fmaxf(fmaxf(a0, a1), fmaxf(a2, a3));
#pragma unroll
        for (int d2 = 4; d2 >= 1; d2 >>= 1) m = fmaxf(m, __shfl_xor(m, d2, 8));
        float ss = __expf(a0 - m) + __expf(a1 - m) + __expf(a2 - m) + __expf(a3 - m);
#pragma unroll
        for (int d2 = 4; d2 >= 1; d2 >>= 1) ss += __shfl_xor(ss, d2, 8);
        float nv = e + m + __logf(ss);
        __syncthreads();
        if (uu == 0 && t < L) alpha[j] = nv;
        __syncthreads();
    }
    if (tid < 32) {
        float v = alpha[tid] + end_trans[tid];
        float m = v;
#pragma unroll
        for (int d2 = 16; d2 >= 1; d2 >>= 1) m = fmaxf(m, __shfl_xor(m, d2, 32));
        float s2 = __expf(v - m);
#pragma unroll
        for (int d2 = 16; d2 >= 1; d2 >>= 1) s2 += __shfl_xor(s2, d2, 32);
        if (tid == 0) out[b] = m + __logf(s2) - goldsh;
    }
}

extern "C" void kernel_launch(void* const* d_in, const int* in_sizes, int n_in,
                              void* d_out, int out_size, void* d_ws, size_t ws_size,
                              hipStream_t stream) {
    if (ws_size < WS_NEED) return;  // workspace too small: fail cleanly, no OOB
    const int* chars = (const int*)d_in[0];
    const int* bigrams = (const int*)d_in[1];
    const int* seq_len = (const int*)d_in[2];
    const int* target = (const int*)d_in[3];
    const float* char_table = (const float*)d_in[4];
    const float* bigram_table = (const float*)d_in[5];
    const float* Wi_f = (const float*)d_in[6];
    const float* Wh_f = (const float*)d_in[7];
    const float* b_f = (const float*)d_in[8];
    const float* Wi_b = (const float*)d_in[9];
    const float* Wh_b = (const float*)d_in[10];
    const float* b_b = (const float*)d_in[11];
    const float* out_W = (const float*)d_in[12];
    const float* out_b = (const float*)d_in[13];
    const float* trans = (const float*)d_in[14];
    const float* start_trans = (const float*)d_in[15];
    const float* end_trans = (const float*)d_in[16];

    char* ws = (char*)d_ws;
    u16* emb = (u16*)(ws + O_EMB);
    u16* xg = (u16*)(ws + O_XG);
    u16* hs = (u16*)(ws + O_HS);
    u16* hst = (u16*)(ws + O_HST);
    float* logits = (float*)(ws + O_LOGITS);
    int* flags = (int*)(ws + O_FLAGS);
    u16* WiT = (u16*)(ws + O_WIT);
    u16* outWb = (u16*)(ws + O_OUTW);

    hipLaunchKernelGGL(k_init, dim3(64), dim3(256), 0, stream, (u32*)hst, flags);
    hipLaunchKernelGGL(k0_prep, dim3(2112), dim3(256), 0, stream, Wi_f, Wi_b, out_W, WiT, outWb);
    hipLaunchKernelGGL(k1_embed, dim3(8192), dim3(256), 0, stream, chars, bigrams, char_table, bigram_table, emb);
    hipLaunchKernelGGL(k2_gemm, dim3(256, 16, 2), dim3(256), 0, stream, emb, WiT, b_f, b_b, xg);
    hipLaunchKernelGGL(k3_lstm, dim3(32), dim3(256), 0, stream, xg, Wh_f, Wh_b, seq_len, hst, hs, flags);
    hipLaunchKernelGGL(k4_proj, dim3(2048), dim3(256), 0, stream, hs, outWb, out_b, logits);
    hipLaunchKernelGGL(k5_crf, dim3(32), dim3(256), 0, stream, logits, target, seq_len, trans, start_trans, end_trans,
                       (float*)d_out);
}

// Round 3
// 2434.494 us; speedup vs baseline: 2.1645x; 1.1838x over previous
//
#include <hip/hip_runtime.h>
#include <cstdint>
#include <cstddef>

typedef unsigned short u16;
typedef unsigned int u32;
typedef unsigned long long u64;

typedef short short8 __attribute__((ext_vector_type(8)));
typedef float floatx4 __attribute__((ext_vector_type(4)));

// Problem constants: B=32, T=512, D=256, H=256, 4H=1024, C=32
// Workspace layout (bytes)
#define O_EMB    0ull                 // emb bf16 [16384][256]
#define O_XG     8388608ull           // xg bf16 [2][16384][1024]
#define O_HS     75497472ull          // hs bf16 [2][16384][256]
#define O_HST    92274688ull          // hstate bf16 [2 dir][2 parity][32][256]
#define O_LOGITS 92340224ull          // logits f32 [16384][32]
#define O_WIT    94437504ull          // WiT bf16 [2][1024][256]
#define O_OUTW   95486080ull          // outW bf16 [512][32]
#define O_FLAGS  95518848ull          // flags: [2 dir][16 w] ints, 64B stride each
#define WS_NEED  95520896ull

__device__ __forceinline__ u16 f2bf(float x) {
    u32 u = __float_as_uint(x);
    u += 0x7fffu + ((u >> 16) & 1u);
    return (u16)(u >> 16);
}
__device__ __forceinline__ float bf2f(u16 v) { return __uint_as_float(((u32)v) << 16); }
__device__ __forceinline__ float sigm(float x) { return 1.0f / (1.0f + __expf(-x)); }
__device__ __forceinline__ float tanh_f(float x) {
    x = fminf(30.0f, fmaxf(-30.0f, x));
    float e = __expf(-2.0f * x);
    return (1.0f - e) / (1.0f + e);
}

// ---------------- K_init: zero h state + sync flags (ws is poisoned each launch) ----
__global__ __launch_bounds__(256) void k_init(u32* hstate_u32, int* flags) {
    int i = blockIdx.x * 256 + threadIdx.x;
    if (i < 16384) hstate_u32[i] = 0u;   // 2*2*32*256 bf16 = 16384 u32
    if (i < 512) flags[i] = 0;           // 2 dirs * 16 flags * 16-int (64B) stride
}

// ---------------- K0: Wi -> WiT bf16 (transposed [n][k]), out_W -> bf16 ------------
__global__ __launch_bounds__(256) void k0_prep(const float* __restrict__ Wi_f, const float* __restrict__ Wi_b,
                                               const float* __restrict__ out_W,
                                               u16* __restrict__ WiT, u16* __restrict__ outWb) {
    int id = blockIdx.x * 256 + threadIdx.x;   // grid 2112*256 = 540672 exact
    if (id < 524288) {
        int d = id >> 18;
        int rem = id & 262143;
        int k = rem >> 10;
        int n = rem & 1023;
        const float* Wi = d ? Wi_b : Wi_f;
        WiT[(size_t)d * 262144 + (size_t)n * 256 + k] = f2bf(Wi[(size_t)k * 1024 + n]);
    } else {
        int id2 = id - 524288;                 // < 16384
        outWb[id2] = f2bf(out_W[id2]);
    }
}

// ---------------- K1: embedding gather -> emb bf16 [r=t*32+b][256] -----------------
__global__ __launch_bounds__(256) void k1_embed(const int* __restrict__ chars, const int* __restrict__ bigrams,
                                                const float* __restrict__ ct, const float* __restrict__ bt,
                                                u16* __restrict__ emb) {
    int idx = blockIdx.x * 256 + threadIdx.x;  // grid 8192*256 = 2097152 = 16384*128
    int r = idx >> 7;
    int p2 = (idx & 127) << 1;
    int t = r >> 5, b = r & 31;
    const float* src;
    if (p2 < 128) src = ct + (size_t)chars[b * 512 + t] * 128 + p2;
    else          src = bt + (size_t)bigrams[b * 512 + t] * 128 + (p2 - 128);
    float2 v = *(const float2*)(const void*)src;
    u32 pk = (u32)f2bf(v.x) | ((u32)f2bf(v.y) << 16);
    *(u32*)(void*)(emb + (size_t)r * 256 + p2) = pk;
}

// ---------------- K2: xg[d][r][n] = emb @ Wi_d + b_d  (bf16 MFMA) ------------------
__global__ __launch_bounds__(256) void k2_gemm(const u16* __restrict__ emb, const u16* __restrict__ WiT,
                                               const float* __restrict__ b_f, const float* __restrict__ b_b,
                                               u16* __restrict__ xg) {
    int mbase = blockIdx.x * 64;
    int nbase = blockIdx.y * 64;
    int d = blockIdx.z;
    const u16* Bt = WiT + (size_t)d * 262144;
    const float* bias = d ? b_b : b_f;
    u16* xgd = xg + (size_t)d * 16777216ull;
    int tid = threadIdx.x;
    int wv = tid >> 6, l = tid & 63, lm = l & 15, lq = l >> 4;
    floatx4 acc[4] = {{0,0,0,0},{0,0,0,0},{0,0,0,0},{0,0,0,0}};
    int arow = mbase + wv * 16 + lm;
#pragma unroll
    for (int kc = 0; kc < 8; ++kc) {
        int k0 = kc * 32 + lq * 8;
        short8 a = *(const short8*)(const void*)(emb + (size_t)arow * 256 + k0);
#pragma unroll
        for (int nt = 0; nt < 4; ++nt) {
            short8 bb = *(const short8*)(const void*)(Bt + (size_t)(nbase + nt * 16 + lm) * 256 + k0);
            acc[nt] = __builtin_amdgcn_mfma_f32_16x16x32_bf16(a, bb, acc[nt], 0, 0, 0);
        }
    }
#pragma unroll
    for (int nt = 0; nt < 4; ++nt) {
        int n = nbase + nt * 16 + lm;
        float bv = bias[n];
#pragma unroll
        for (int r = 0; r < 4; ++r) {
            int rr = mbase + wv * 16 + lq * 4 + r;
            xgd[(size_t)rr * 1024 + n] = f2bf(acc[nt][r] + bv);
        }
    }
}

// ---------------- K3: BiLSTM recurrence -------------------------------------------
// 32 blocks: dir = bid>>4, w = bid&15. WG w owns h dims [16w,16w+16); Wh slice in LDS.
// Cross-block h exchange: agent-scope RELAXED atomics (write-through, L3-coherent).
// Sync per step: wave0 polls 16 cache-line-padded flags (s_sleep backoff) -> barrier;
// tail: write-through h store -> barrier (vmcnt drain = release ordering) -> RELAXED
// flag store (no release => no buffer_wbl2 L2 writeback on the critical path) ->
// plain hs history store (off critical path, flushed at kernel end for k4).
__global__ __launch_bounds__(256) void k3_lstm(const u16* __restrict__ xg, const float* __restrict__ Wh_f,
                                               const float* __restrict__ Wh_b, const int* __restrict__ seq_len,
                                               u16* __restrict__ hstate, u16* __restrict__ hs,
                                               int* __restrict__ flags) {
    int bid = blockIdx.x;
    int dir = bid >> 4;
    int w = bid & 15;
    const float* Wh = dir ? Wh_b : Wh_f;
    const u16* xgd = xg + (size_t)dir * 16777216ull;
    u16* hsd = hs + (size_t)dir * 4194304ull;
    __shared__ u16 lds_w[64 * 264];      // [p=g*16+c][k], padded pitch 264
    __shared__ float gate_lds[32 * 68];  // [b][p], padded pitch 68
    int tid = threadIdx.x;

    // Stage Wh slice: cols gcol = g*256 + 16w + c, transposed into lds_w[p][k]
    for (int it = 0; it < 64; ++it) {
        int e = it * 256 + tid;
        int p = e & 63;
        int k = e >> 6;
        int gcol = (p >> 4) * 256 + w * 16 + (p & 15);
        lds_w[p * 264 + k] = f2bf(Wh[(size_t)k * 1024 + gcol]);
    }
    int bcell = tid >> 3, uu = tid & 7, c0 = uu * 2;   // this thread owns cells (bcell, c0..c0+1)
    int L = seq_len[bcell];
    float cst0 = 0.0f, cst1 = 0.0f;
    int wv = tid >> 6, l = tid & 63, lm = l & 15, lq = l >> 4, mt = wv & 1, nh = wv >> 1;
    int* myflags = flags + dir * 256;    // 16 flags, each on its own 64B line (stride 16 ints)
    __syncthreads();

    for (int s = 0; s < 512; ++s) {
        int t = dir ? (511 - s) : s;
        // prefetch xg (independent of sync) : 4 gates x 2 bf16
        u32 xgv[4];
        const u16* xrow = xgd + ((size_t)(t * 32 + bcell)) * 1024 + w * 16 + c0;
#pragma unroll
        for (int g = 0; g < 4; ++g) xgv[g] = *(const u32*)(const void*)(xrow + g * 256);

        if (s > 0) {
            if (tid < 64) {   // wave 0 polls; lanes 16-63 ride along (uniform exit via ballot)
                for (;;) {
                    int v = (tid < 16)
                        ? __hip_atomic_load(&myflags[tid * 16], __ATOMIC_RELAXED, __HIP_MEMORY_SCOPE_AGENT)
                        : 0x7fffffff;
                    if (__ballot(v >= s) == ~0ull) break;
                    __builtin_amdgcn_s_sleep(1);
                }
            }
            __syncthreads();
            __builtin_amdgcn_sched_barrier(0);   // keep h loads below the poll
        }
        // A-fragments straight from coherent (L3) atomic u64 loads
        const u64* hbq = (const u64*)(const void*)(hstate + ((size_t)(dir * 2 + (s & 1))) * 8192);
        int arowh = mt * 16 + lm;
        u64 aq[16];
#pragma unroll
        for (int kc = 0; kc < 8; ++kc) {
            size_t qi = (size_t)arowh * 64 + (size_t)kc * 8 + lq * 2;
            aq[2 * kc]     = __hip_atomic_load(hbq + qi,     __ATOMIC_RELAXED, __HIP_MEMORY_SCOPE_AGENT);
            aq[2 * kc + 1] = __hip_atomic_load(hbq + qi + 1, __ATOMIC_RELAXED, __HIP_MEMORY_SCOPE_AGENT);
        }
        floatx4 acc0 = {0,0,0,0}, acc1 = {0,0,0,0};
#pragma unroll
        for (int kc = 0; kc < 8; ++kc) {
            union { u64 q[2]; short8 s8; } ua;
            ua.q[0] = aq[2 * kc];
            ua.q[1] = aq[2 * kc + 1];
            int k0 = kc * 32 + lq * 8;
            short8 b0 = *(const short8*)(const void*)&lds_w[(nh * 32 + lm) * 264 + k0];
            acc0 = __builtin_amdgcn_mfma_f32_16x16x32_bf16(ua.s8, b0, acc0, 0, 0, 0);
            short8 b1 = *(const short8*)(const void*)&lds_w[(nh * 32 + 16 + lm) * 264 + k0];
            acc1 = __builtin_amdgcn_mfma_f32_16x16x32_bf16(ua.s8, b1, acc1, 0, 0, 0);
        }
#pragma unroll
        for (int r = 0; r < 4; ++r) {
            int b2 = mt * 16 + lq * 4 + r;
            gate_lds[b2 * 68 + nh * 32 + lm] = acc0[r];
            gate_lds[b2 * 68 + nh * 32 + 16 + lm] = acc1[r];
        }
        __syncthreads();
        float hv0, hv1;
#pragma unroll
        for (int r = 0; r < 2; ++r) {
            int cc = c0 + r;
            float gi = gate_lds[bcell * 68 + cc]      + bf2f((u16)(xgv[0] >> (16 * r)));
            float gf = gate_lds[bcell * 68 + 16 + cc] + bf2f((u16)(xgv[1] >> (16 * r)));
            float gg = gate_lds[bcell * 68 + 32 + cc] + bf2f((u16)(xgv[2] >> (16 * r)));
            float go = gate_lds[bcell * 68 + 48 + cc] + bf2f((u16)(xgv[3] >> (16 * r)));
            float ig = sigm(gi), fg = sigm(gf), gt = tanh_f(gg), og = sigm(go);
            float cs = r ? cst1 : cst0;
            float cn = fg * cs + ig * gt;
            float hn = og * tanh_f(cn);
            if (dir && t >= L) { cn = cs; hn = 0.0f; }   // backward: masked prefix carries zeros
            if (r) { cst1 = cn; hv1 = hn; } else { cst0 = cn; hv0 = hn; }
        }
        u32 hpack = (u32)f2bf(hv0) | ((u32)f2bf(hv1) << 16);
        u32* hbn = (u32*)(void*)(hstate + ((size_t)(dir * 2 + ((s + 1) & 1))) * 8192 + bcell * 256 + w * 16 + c0);
        __hip_atomic_store(hbn, hpack, __ATOMIC_RELAXED, __HIP_MEMORY_SCOPE_AGENT);
        __syncthreads();   // vmcnt(0) drain of ALL waves' write-through h stores = release ordering
        if (tid == 0) __hip_atomic_store(&myflags[w * 16], s + 1, __ATOMIC_RELAXED, __HIP_MEMORY_SCOPE_AGENT);
        // hs history: plain L2-cached store, off the critical path (k4 reads after kernel end)
        *(u32*)(void*)(hsd + ((size_t)(t * 32 + bcell)) * 256 + w * 16 + c0) = hpack;
    }
}

// ---------------- K4: logits = log_softmax([hf;hb] @ out_W + out_b) ---------------
__global__ __launch_bounds__(256) void k4_proj(const u16* __restrict__ hs, const u16* __restrict__ outWb,
                                               const float* __restrict__ out_b, float* __restrict__ logits) {
    int r = blockIdx.x * 8 + (threadIdx.x >> 5);
    int n = threadIdx.x & 31;
    const u16* hf = hs + (size_t)r * 256;
    const u16* hbk = hs + 4194304ull + (size_t)r * 256;
    float acc = out_b[n];
#pragma unroll 4
    for (int k = 0; k < 256; k += 2) {
        u32 hv = *(const u32*)(const void*)(hf + k);
        acc += bf2f((u16)hv) * bf2f(outWb[k * 32 + n]);
        acc += bf2f((u16)(hv >> 16)) * bf2f(outWb[(k + 1) * 32 + n]);
    }
#pragma unroll 4
    for (int k = 0; k < 256; k += 2) {
        u32 hv = *(const u32*)(const void*)(hbk + k);
        acc += bf2f((u16)hv) * bf2f(outWb[(256 + k) * 32 + n]);
        acc += bf2f((u16)(hv >> 16)) * bf2f(outWb[(257 + k) * 32 + n]);
    }
    float m = acc;
#pragma unroll
    for (int d2 = 16; d2 >= 1; d2 >>= 1) m = fmaxf(m, __shfl_xor(m, d2, 32));
    float s = __expf(acc - m);
#pragma unroll
    for (int d2 = 16; d2 >= 1; d2 >>= 1) s += __shfl_xor(s, d2, 32);
    logits[(size_t)r * 32 + n] = acc - m - __logf(s);
}

// ---------------- K5: CRF forward + gold score -> out[b] --------------------------
__global__ __launch_bounds__(256) void k5_crf(const float* __restrict__ logits, const int* __restrict__ target,
                                              const int* __restrict__ seq_len, const float* __restrict__ trans,
                                              const float* __restrict__ start_trans, const float* __restrict__ end_trans,
                                              float* __restrict__ out) {
    int b = blockIdx.x;
    int tid = threadIdx.x;
    int L = seq_len[b];
    __shared__ float alpha[32];
    __shared__ float red[4];
    __shared__ float goldsh;

    // gold path score
    float part = 0.0f;
    for (int t = tid; t < 512; t += 256) {
        if (t < L) {
            int tg = target[b * 512 + t];
            part += logits[((size_t)(t * 32 + b)) * 32 + tg];
            if (t >= 1) part += trans[target[b * 512 + t - 1] * 32 + tg];
        }
    }
#pragma unroll
    for (int d2 = 32; d2 >= 1; d2 >>= 1) part += __shfl_xor(part, d2, 64);
    if ((tid & 63) == 0) red[tid >> 6] = part;
    __syncthreads();
    if (tid == 0) {
        float g = red[0] + red[1] + red[2] + red[3];
        g += start_trans[target[b * 512]];
        g += end_trans[target[b * 512 + L - 1]];
        goldsh = g;
    }
    if (tid < 32) alpha[tid] = logits[(size_t)b * 32 + tid] + start_trans[tid];
    __syncthreads();

    int j = tid >> 3, uu = tid & 7;
    float tr4[4];
#pragma unroll
    for (int r = 0; r < 4; ++r) tr4[r] = trans[(uu * 4 + r) * 32 + j];
    float e_next = logits[((size_t)(32 + b)) * 32 + j];
    for (int t = 1; t < 512; ++t) {
        float e = e_next;
        if (t < 511) e_next = logits[((size_t)((t + 1) * 32 + b)) * 32 + j];
        float a0 = alpha[uu * 4 + 0] + tr4[0];
        float a1 = alpha[uu * 4 + 1] + tr4[1];
        float a2 = alpha[uu * 4 + 2] + tr4[2];
        float a3 = alpha[uu * 4 + 3] + tr4[3];
        float m = fmaxf(fmaxf(a0, a1), fmaxf(a2, a3));
#pragma unroll
        for (int d2 = 4; d2 >= 1; d2 >>= 1) m = fmaxf(m, __shfl_xor(m, d2, 8));
        float ss = __expf(a0 - m) + __expf(a1 - m) + __expf(a2 - m) + __expf(a3 - m);
#pragma unroll
        for (int d2 = 4; d2 >= 1; d2 >>= 1) ss += __shfl_xor(ss, d2, 8);
        float nv = e + m + __logf(ss);
        __syncthreads();
        if (uu == 0 && t < L) alpha[j] = nv;
        __syncthreads();
    }
    if (tid < 32) {
        float v = alpha[tid] + end_trans[tid];
        float m = v;
#pragma unroll
        for (int d2 = 16; d2 >= 1; d2 >>= 1) m = fmaxf(m, __shfl_xor(m, d2, 32));
        float s2 = __expf(v - m);
#pragma unroll
        for (int d2 = 16; d2 >= 1; d2 >>= 1) s2 += __shfl_xor(s2, d2, 32);
        if (tid == 0) out[b] = m + __logf(s2) - goldsh;
    }
}

extern "C" void kernel_launch(void* const* d_in, const int* in_sizes, int n_in,
                              void* d_out, int out_size, void* d_ws, size_t ws_size,
                              hipStream_t stream) {
    if (ws_size < WS_NEED) return;  // workspace too small: fail cleanly, no OOB
    const int* chars = (const int*)d_in[0];
    const int* bigrams = (const int*)d_in[1];
    const int* seq_len = (const int*)d_in[2];
    const int* target = (const int*)d_in[3];
    const float* char_table = (const float*)d_in[4];
    const float* bigram_table = (const float*)d_in[5];
    const float* Wi_f = (const float*)d_in[6];
    const float* Wh_f = (const float*)d_in[7];
    const float* b_f = (const float*)d_in[8];
    const float* Wi_b = (const float*)d_in[9];
    const float* Wh_b = (const float*)d_in[10];
    const float* b_b = (const float*)d_in[11];
    const float* out_W = (const float*)d_in[12];
    const float* out_b = (const float*)d_in[13];
    const float* trans = (const float*)d_in[14];
    const float* start_trans = (const float*)d_in[15];
    const float* end_trans = (const float*)d_in[16];

    char* ws = (char*)d_ws;
    u16* emb = (u16*)(ws + O_EMB);
    u16* xg = (u16*)(ws + O_XG);
    u16* hs = (u16*)(ws + O_HS);
    u16* hst = (u16*)(ws + O_HST);
    float* logits = (float*)(ws + O_LOGITS);
    int* flags = (int*)(ws + O_FLAGS);
    u16* WiT = (u16*)(ws + O_WIT);
    u16* outWb = (u16*)(ws + O_OUTW);

    hipLaunchKernelGGL(k_init, dim3(64), dim3(256), 0, stream, (u32*)hst, flags);
    hipLaunchKernelGGL(k0_prep, dim3(2112), dim3(256), 0, stream, Wi_f, Wi_b, out_W, WiT, outWb);
    hipLaunchKernelGGL(k1_embed, dim3(8192), dim3(256), 0, stream, chars, bigrams, char_table, bigram_table, emb);
    hipLaunchKernelGGL(k2_gemm, dim3(256, 16, 2), dim3(256), 0, stream, emb, WiT, b_f, b_b, xg);
    hipLaunchKernelGGL(k3_lstm, dim3(32), dim3(256), 0, stream, xg, Wh_f, Wh_b, seq_len, hst, hs, flags);
    hipLaunchKernelGGL(k4_proj, dim3(2048), dim3(256), 0, stream, hs, outWb, out_b, logits);
    hipLaunchKernelGGL(k5_crf, dim3(32), dim3(256), 0, stream, logits, target, seq_len, trans, start_trans, end_trans,
                       (float*)d_out);
}